// Round 1
// baseline (535.074 us; speedup 1.0000x reference)
//
#include <hip/hip_runtime.h>
#include <cstdint>
#include <cstddef>

// Problem constants
#define TD 512     // d_model
#define TF 2048    // d_ff
#define NE 8       // experts
#define NT 8192    // tokens (B*S)
#define CAP 17408  // padded assignment slots: 16384 + 8*128

using u16 = unsigned short;
using u32 = unsigned int;

typedef __attribute__((ext_vector_type(8))) __bf16 bf16x8;
typedef __attribute__((ext_vector_type(4))) float f32x4;

__device__ __forceinline__ u16 f2bf(float f) {
  // round-to-nearest-even fp32 -> bf16 (no NaN inputs expected)
  u32 u = __float_as_uint(f);
  u32 r = (u + 0x7fffu + ((u >> 16) & 1u)) >> 16;
  return (u16)r;
}

// ---------------- K0: zero output + counts ----------------
__global__ void zero_kernel(float* __restrict__ out, int* __restrict__ counts) {
  int i = blockIdx.x * 256 + threadIdx.x;
  if (i < NE) counts[i] = 0;
  float4 z = make_float4(0.f, 0.f, 0.f, 0.f);
  *reinterpret_cast<float4*>(out + (size_t)i * 4) = z;
}

// ---------------- K1: convert x fp32 -> bf16 ----------------
__global__ void cvt_x_kernel(const float* __restrict__ x, u16* __restrict__ xb) {
  int i = (blockIdx.x * 256 + threadIdx.x) * 8;
  float4 a = *reinterpret_cast<const float4*>(x + i);
  float4 b = *reinterpret_cast<const float4*>(x + i + 4);
  u16 o[8];
  o[0] = f2bf(a.x); o[1] = f2bf(a.y); o[2] = f2bf(a.z); o[3] = f2bf(a.w);
  o[4] = f2bf(b.x); o[5] = f2bf(b.y); o[6] = f2bf(b.z); o[7] = f2bf(b.w);
  *reinterpret_cast<uint4*>(xb + i) = *reinterpret_cast<uint4*>(o);
}

// ---------------- K2: transpose + convert weights ----------------
// out[c*R + r] = bf16(in[r*C + c]) per expert (blockIdx.z)
__global__ void transpose_cvt_kernel(const float* __restrict__ in, u16* __restrict__ out,
                                     int R, int C) {
  __shared__ u16 tile[32][33];
  int c0 = blockIdx.x * 32, r0 = blockIdx.y * 32;
  const float* ib = in + (size_t)blockIdx.z * R * C;
  u16* ob = out + (size_t)blockIdx.z * R * C;
  #pragma unroll
  for (int rr = 0; rr < 32; rr += 8) {
    int r = r0 + threadIdx.y + rr;
    int c = c0 + threadIdx.x;
    tile[threadIdx.y + rr][threadIdx.x] = f2bf(ib[(size_t)r * C + c]);
  }
  __syncthreads();
  #pragma unroll
  for (int rr = 0; rr < 32; rr += 8) {
    int oc = c0 + threadIdx.y + rr;   // output row (= input col)
    int orr = r0 + threadIdx.x;       // output col (= input row)
    ob[(size_t)oc * R + orr] = tile[threadIdx.x][threadIdx.y + rr];
  }
}

// ---------------- K3: router (one wave per token) ----------------
__global__ void router_kernel(const float* __restrict__ x, const float* __restrict__ rw,
                              const float* __restrict__ rb, int2* __restrict__ tokE,
                              float2* __restrict__ tokG, int* __restrict__ counts) {
  int wv = threadIdx.x >> 6;
  int lane = threadIdx.x & 63;
  int t = blockIdx.x * 4 + wv;
  const float* xr = x + (size_t)t * TD + lane * 8;
  float p[NE];
  #pragma unroll
  for (int e = 0; e < NE; e++) p[e] = 0.f;
  #pragma unroll
  for (int j = 0; j < 8; j++) {
    float xv = xr[j];
    const float* r = rw + (size_t)(lane * 8 + j) * NE;
    #pragma unroll
    for (int e = 0; e < NE; e++) p[e] += xv * r[e];
  }
  #pragma unroll
  for (int off = 32; off >= 1; off >>= 1) {
    #pragma unroll
    for (int e = 0; e < NE; e++) p[e] += __shfl_xor(p[e], off);
  }
  if (lane == 0) {
    float l[NE];
    #pragma unroll
    for (int e = 0; e < NE; e++) l[e] = p[e] + rb[e];
    float m = l[0];
    #pragma unroll
    for (int e = 1; e < NE; e++) m = fmaxf(m, l[e]);
    float g[NE];
    #pragma unroll
    for (int e = 0; e < NE; e++) g[e] = __expf(l[e] - m);
    // top-2 by gate (== top-2 by logit); ties -> lower index first (jax top_k)
    int i0 = 0;
    #pragma unroll
    for (int e = 1; e < NE; e++) if (g[e] > g[i0]) i0 = e;
    int i1 = -1;
    #pragma unroll
    for (int e = 0; e < NE; e++) {
      if (e == i0) continue;
      if (i1 < 0 || g[e] > g[i1]) i1 = e;
    }
    float inv = 1.f / (g[i0] + g[i1]);
    tokE[t] = make_int2(i0, i1);
    tokG[t] = make_float2(g[i0] * inv, g[i1] * inv);
    atomicAdd(&counts[i0], 1);
    atomicAdd(&counts[i1], 1);
  }
}

// ---------------- K4: prefix offsets (128-aligned) ----------------
__global__ void offsets_kernel(const int* __restrict__ counts, int* __restrict__ offs,
                               int* __restrict__ cursors) {
  if (threadIdx.x == 0) {
    int tot = 0;
    for (int e = 0; e < NE; e++) {
      offs[e] = tot;
      tot += (counts[e] + 127) & ~127;
    }
    offs[NE] = tot;
  }
  if (threadIdx.x < NE) cursors[threadIdx.x] = 0;
}

// ---------------- K5: fill slot metadata defaults ----------------
__global__ void fill_kernel(const int* __restrict__ offs, int* __restrict__ tok,
                            float* __restrict__ gate, int* __restrict__ sexp) {
  int s = blockIdx.x * 256 + threadIdx.x;
  if (s >= CAP) return;
  int e = NE - 1;
  #pragma unroll
  for (int i = 0; i < NE; i++)
    if (s >= offs[i] && s < offs[i + 1]) e = i;
  sexp[s] = e;
  tok[s] = -1;
  gate[s] = 0.f;
}

// ---------------- K6: scatter assignments into slots ----------------
__global__ void scatter_kernel(const int2* __restrict__ tokE, const float2* __restrict__ tokG,
                               const int* __restrict__ offs, int* __restrict__ cursors,
                               int* __restrict__ tok, float* __restrict__ gate) {
  int t = blockIdx.x * 256 + threadIdx.x;
  if (t >= NT) return;
  int2 e = tokE[t];
  float2 g = tokG[t];
  int p0 = atomicAdd(&cursors[e.x], 1);
  int s0 = offs[e.x] + p0;
  tok[s0] = t; gate[s0] = g.x;
  int p1 = atomicAdd(&cursors[e.y], 1);
  int s1 = offs[e.y] + p1;
  tok[s1] = t; gate[s1] = g.y;
}

// ---------------- K7: GEMM1  H = relu(x_gather @ W1 + b1), bf16 out ----------------
// grid (CAP/128, TF/128), block 256 (4 waves, 2x2 of 64x64)
__global__ __launch_bounds__(256, 2) void gemm1_kernel(
    const u16* __restrict__ xb, const u16* __restrict__ w1t,
    const float* __restrict__ b1, const int* __restrict__ tok,
    const int* __restrict__ sexp, u16* __restrict__ H) {
  __shared__ u16 As[128 * 72];
  __shared__ u16 Bs[128 * 72];
  __shared__ int tokS[128];
  const int tid = threadIdx.x;
  const int s0 = blockIdx.x * 128;
  const int f0 = blockIdx.y * 128;
  const int e = sexp[s0];
  if (tid < 128) {
    int t = tok[s0 + tid];
    tokS[tid] = t < 0 ? 0 : t;  // padding rows read token 0 (result discarded)
  }
  __syncthreads();

  const int lane = tid & 63;
  const int wv = tid >> 6;
  const int wm = (wv >> 1) * 64;
  const int wn = (wv & 1) * 64;
  const int mrow = lane & 15;
  const int koff = (lane >> 4) * 8;

  f32x4 zero = {0.f, 0.f, 0.f, 0.f};
  f32x4 acc[4][4];
  #pragma unroll
  for (int i = 0; i < 4; i++)
    #pragma unroll
    for (int j = 0; j < 4; j++) acc[i][j] = zero;

  const u16* bbase = w1t + ((size_t)e * TF + f0) * TD;

  for (int k0 = 0; k0 < TD; k0 += 64) {
    if (k0) __syncthreads();
    #pragma unroll
    for (int p = 0; p < 4; p++) {
      int lin = p * 2048 + tid * 8;
      int row = lin >> 6, col = lin & 63;
      uint4 v = *reinterpret_cast<const uint4*>(xb + (size_t)tokS[row] * TD + k0 + col);
      *reinterpret_cast<uint4*>(&As[row * 72 + col]) = v;
    }
    #pragma unroll
    for (int p = 0; p < 4; p++) {
      int lin = p * 2048 + tid * 8;
      int row = lin >> 6, col = lin & 63;
      uint4 v = *reinterpret_cast<const uint4*>(bbase + (size_t)row * TD + k0 + col);
      *reinterpret_cast<uint4*>(&Bs[row * 72 + col]) = v;
    }
    __syncthreads();
    #pragma unroll
    for (int ks = 0; ks < 2; ks++) {
      bf16x8 a[4], b[4];
      #pragma unroll
      for (int i = 0; i < 4; i++)
        a[i] = *reinterpret_cast<const bf16x8*>(&As[(wm + i * 16 + mrow) * 72 + ks * 32 + koff]);
      #pragma unroll
      for (int j = 0; j < 4; j++)
        b[j] = *reinterpret_cast<const bf16x8*>(&Bs[(wn + j * 16 + mrow) * 72 + ks * 32 + koff]);
      #pragma unroll
      for (int i = 0; i < 4; i++)
        #pragma unroll
        for (int j = 0; j < 4; j++)
          acc[i][j] = __builtin_amdgcn_mfma_f32_16x16x32_bf16(a[i], b[j], acc[i][j], 0, 0, 0);
    }
  }

  const int quad = lane >> 4;
  float bv[4];
  #pragma unroll
  for (int j = 0; j < 4; j++) bv[j] = b1[e * TF + f0 + wn + j * 16 + mrow];
  #pragma unroll
  for (int i = 0; i < 4; i++) {
    #pragma unroll
    for (int r = 0; r < 4; r++) {
      int row = s0 + wm + i * 16 + quad * 4 + r;
      u16* hrow = H + (size_t)row * TF + f0;
      #pragma unroll
      for (int j = 0; j < 4; j++) {
        float v = acc[i][j][r] + bv[j];
        v = v > 0.f ? v : 0.f;
        hrow[wn + j * 16 + mrow] = f2bf(v);
      }
    }
  }
}

// ---------------- K8: GEMM2  out[tok] += gate * (H @ W2 + b2) ----------------
// grid (CAP/128, TD/128), block 256
__global__ __launch_bounds__(256, 2) void gemm2_kernel(
    const u16* __restrict__ H, const u16* __restrict__ w2t,
    const float* __restrict__ b2, const int* __restrict__ tok,
    const float* __restrict__ gate, const int* __restrict__ sexp,
    float* __restrict__ out) {
  __shared__ u16 As[128 * 72];
  __shared__ u16 Bs[128 * 72];
  __shared__ int tokS[128];
  __shared__ float gateS[128];
  const int tid = threadIdx.x;
  const int s0 = blockIdx.x * 128;
  const int d0 = blockIdx.y * 128;
  const int e = sexp[s0];
  if (tid < 128) {
    tokS[tid] = tok[s0 + tid];
    gateS[tid] = gate[s0 + tid];
  }
  __syncthreads();

  const int lane = tid & 63;
  const int wv = tid >> 6;
  const int wm = (wv >> 1) * 64;
  const int wn = (wv & 1) * 64;
  const int mrow = lane & 15;
  const int koff = (lane >> 4) * 8;

  f32x4 zero = {0.f, 0.f, 0.f, 0.f};
  f32x4 acc[4][4];
  #pragma unroll
  for (int i = 0; i < 4; i++)
    #pragma unroll
    for (int j = 0; j < 4; j++) acc[i][j] = zero;

  const u16* bbase = w2t + ((size_t)e * TD + d0) * TF;

  for (int k0 = 0; k0 < TF; k0 += 64) {
    if (k0) __syncthreads();
    #pragma unroll
    for (int p = 0; p < 4; p++) {
      int lin = p * 2048 + tid * 8;
      int row = lin >> 6, col = lin & 63;
      uint4 v = *reinterpret_cast<const uint4*>(H + (size_t)(s0 + row) * TF + k0 + col);
      *reinterpret_cast<uint4*>(&As[row * 72 + col]) = v;
    }
    #pragma unroll
    for (int p = 0; p < 4; p++) {
      int lin = p * 2048 + tid * 8;
      int row = lin >> 6, col = lin & 63;
      uint4 v = *reinterpret_cast<const uint4*>(bbase + (size_t)row * TF + k0 + col);
      *reinterpret_cast<uint4*>(&Bs[row * 72 + col]) = v;
    }
    __syncthreads();
    #pragma unroll
    for (int ks = 0; ks < 2; ks++) {
      bf16x8 a[4], b[4];
      #pragma unroll
      for (int i = 0; i < 4; i++)
        a[i] = *reinterpret_cast<const bf16x8*>(&As[(wm + i * 16 + mrow) * 72 + ks * 32 + koff]);
      #pragma unroll
      for (int j = 0; j < 4; j++)
        b[j] = *reinterpret_cast<const bf16x8*>(&Bs[(wn + j * 16 + mrow) * 72 + ks * 32 + koff]);
      #pragma unroll
      for (int i = 0; i < 4; i++)
        #pragma unroll
        for (int j = 0; j < 4; j++)
          acc[i][j] = __builtin_amdgcn_mfma_f32_16x16x32_bf16(a[i], b[j], acc[i][j], 0, 0, 0);
    }
  }

  const int quad = lane >> 4;
  float bv[4];
  #pragma unroll
  for (int j = 0; j < 4; j++) bv[j] = b2[e * TD + d0 + wn + j * 16 + mrow];
  #pragma unroll
  for (int i = 0; i < 4; i++) {
    #pragma unroll
    for (int r = 0; r < 4; r++) {
      int rl = wm + i * 16 + quad * 4 + r;
      int t = tokS[rl];
      if (t < 0) continue;
      float g = gateS[rl];
      float* orow = out + (size_t)t * TD + d0;
      #pragma unroll
      for (int j = 0; j < 4; j++) {
        atomicAdd(&orow[wn + j * 16 + mrow], g * (acc[i][j][r] + bv[j]));
      }
    }
  }
}

extern "C" void kernel_launch(void* const* d_in, const int* in_sizes, int n_in,
                              void* d_out, int out_size, void* d_ws, size_t ws_size,
                              hipStream_t stream) {
  const float* x  = (const float*)d_in[0];
  const float* rw = (const float*)d_in[1];
  const float* rb = (const float*)d_in[2];
  const float* w1 = (const float*)d_in[3];
  const float* b1 = (const float*)d_in[4];
  const float* w2 = (const float*)d_in[5];
  const float* b2 = (const float*)d_in[6];
  float* out = (float*)d_out;

  char* w = (char*)d_ws;
  u16* xb   = (u16*)w;            w += (size_t)NT * TD * 2;         // 8 MB
  u16* w1t  = (u16*)w;            w += (size_t)NE * TD * TF * 2;    // 16 MB
  u16* w2t  = (u16*)w;            w += (size_t)NE * TF * TD * 2;    // 16 MB
  u16* H    = (u16*)w;            w += (size_t)CAP * TF * 2;        // 68 MB
  int* tok  = (int*)w;            w += (size_t)CAP * 4;
  float* gate = (float*)w;        w += (size_t)CAP * 4;
  int* sexp = (int*)w;            w += (size_t)CAP * 4;
  int2* tokE = (int2*)w;          w += (size_t)NT * 8;
  float2* tokG = (float2*)w;      w += (size_t)NT * 8;
  int* counts = (int*)w;          w += 256;
  int* cursors = (int*)w;         w += 256;
  int* offs = (int*)w;            w += 256;

  // 1. zero output + expert counts
  zero_kernel<<<dim3((NT * TD) / (256 * 4)), dim3(256), 0, stream>>>(out, counts);
  // 2. convert x to bf16
  cvt_x_kernel<<<dim3((NT * TD) / (256 * 8)), dim3(256), 0, stream>>>(x, xb);
  // 3. transpose+convert w1 [E][D][F] -> w1t [E][F][D]
  transpose_cvt_kernel<<<dim3(TF / 32, TD / 32, NE), dim3(32, 8), 0, stream>>>(w1, w1t, TD, TF);
  // 4. transpose+convert w2 [E][F][D] -> w2t [E][D][F]
  transpose_cvt_kernel<<<dim3(TD / 32, TF / 32, NE), dim3(32, 8), 0, stream>>>(w2, w2t, TF, TD);
  // 5. router
  router_kernel<<<dim3(NT / 4), dim3(256), 0, stream>>>(x, rw, rb, tokE, tokG, counts);
  // 6. offsets
  offsets_kernel<<<dim3(1), dim3(64), 0, stream>>>(counts, offs, cursors);
  // 7. fill slot defaults
  fill_kernel<<<dim3(CAP / 256), dim3(256), 0, stream>>>(offs, tok, gate, sexp);
  // 8. scatter assignments
  scatter_kernel<<<dim3(NT / 256), dim3(256), 0, stream>>>(tokE, tokG, offs, cursors, tok, gate);
  // 9. GEMM1
  gemm1_kernel<<<dim3(CAP / 128, TF / 128), dim3(256), 0, stream>>>(xb, w1t, b1, tok, sexp, H);
  // 10. GEMM2 + scatter-add epilogue
  gemm2_kernel<<<dim3(CAP / 128, TD / 128), dim3(256), 0, stream>>>(H, w2t, b2, tok, gate, sexp, out);
}

// Round 2
// 304.471 us; speedup vs baseline: 1.7574x; 1.7574x over previous
//
#include <hip/hip_runtime.h>
#include <cstdint>
#include <cstddef>

// Problem constants
#define TD 512     // d_model
#define TF 2048    // d_ff
#define NE 8       // experts
#define NT 8192    // tokens (B*S)
#define CAP 17408  // padded assignment slots: 16384 + 8*128

using u16 = unsigned short;
using u32 = unsigned int;

typedef __attribute__((ext_vector_type(8))) __bf16 bf16x8;
typedef __attribute__((ext_vector_type(4))) float f32x4;

__device__ __forceinline__ u16 f2bf(float f) {
  // round-to-nearest-even fp32 -> bf16 (no NaN inputs expected)
  u32 u = __float_as_uint(f);
  u32 r = (u + 0x7fffu + ((u >> 16) & 1u)) >> 16;
  return (u16)r;
}

// async global->LDS, 16B per lane; LDS dest = wave-uniform base + lane*16
__device__ __forceinline__ void load_lds16(const void* g, void* l) {
  __builtin_amdgcn_global_load_lds(
      (const __attribute__((address_space(1))) void*)g,
      (__attribute__((address_space(3))) void*)l, 16, 0, 0);
}

// ---------------- K0: zero output ----------------
__global__ void zero_kernel(float* __restrict__ out) {
  int i = blockIdx.x * 256 + threadIdx.x;
  float4 z = make_float4(0.f, 0.f, 0.f, 0.f);
  *reinterpret_cast<float4*>(out + (size_t)i * 4) = z;
}

// ---------------- K2: transpose + convert weights ----------------
// out[c*R + r] = bf16(in[r*C + c]) per expert (blockIdx.z)
__global__ void transpose_cvt_kernel(const float* __restrict__ in, u16* __restrict__ out,
                                     int R, int C) {
  __shared__ u16 tile[32][33];
  int c0 = blockIdx.x * 32, r0 = blockIdx.y * 32;
  const float* ib = in + (size_t)blockIdx.z * R * C;
  u16* ob = out + (size_t)blockIdx.z * R * C;
  #pragma unroll
  for (int rr = 0; rr < 32; rr += 8) {
    int r = r0 + threadIdx.y + rr;
    int c = c0 + threadIdx.x;
    tile[threadIdx.y + rr][threadIdx.x] = f2bf(ib[(size_t)r * C + c]);
  }
  __syncthreads();
  #pragma unroll
  for (int rr = 0; rr < 32; rr += 8) {
    int oc = c0 + threadIdx.y + rr;   // output row (= input col)
    int orr = r0 + threadIdx.x;       // output col (= input row)
    ob[(size_t)oc * R + orr] = tile[threadIdx.x][threadIdx.y + rr];
  }
}

// ---------------- K3: router (one wave per token, NO atomics) + x->bf16 ----------------
__global__ void router_kernel(const float* __restrict__ x, const float* __restrict__ rw,
                              const float* __restrict__ rb, int2* __restrict__ tokE,
                              float2* __restrict__ tokG, u16* __restrict__ xb) {
  int wv = threadIdx.x >> 6;
  int lane = threadIdx.x & 63;
  int t = blockIdx.x * 4 + wv;
  const float* xr = x + (size_t)t * TD;
  float4 a0 = *reinterpret_cast<const float4*>(xr + lane * 4);
  float4 a1 = *reinterpret_cast<const float4*>(xr + 256 + lane * 4);
  // fused x -> bf16 conversion (coalesced 8B stores)
  {
    u16 o[8];
    o[0] = f2bf(a0.x); o[1] = f2bf(a0.y); o[2] = f2bf(a0.z); o[3] = f2bf(a0.w);
    o[4] = f2bf(a1.x); o[5] = f2bf(a1.y); o[6] = f2bf(a1.z); o[7] = f2bf(a1.w);
    u16* xo = xb + (size_t)t * TD;
    *reinterpret_cast<uint2*>(xo + lane * 4) = *reinterpret_cast<uint2*>(o);
    *reinterpret_cast<uint2*>(xo + 256 + lane * 4) = *reinterpret_cast<uint2*>(o + 4);
  }
  float p[NE];
  #pragma unroll
  for (int e = 0; e < NE; e++) p[e] = 0.f;
  float av[8] = {a0.x, a0.y, a0.z, a0.w, a1.x, a1.y, a1.z, a1.w};
  #pragma unroll
  for (int j = 0; j < 8; j++) {
    int d = (j < 4) ? (lane * 4 + j) : (256 + lane * 4 + j - 4);
    const float* r = rw + (size_t)d * NE;
    #pragma unroll
    for (int e = 0; e < NE; e++) p[e] += av[j] * r[e];
  }
  #pragma unroll
  for (int off = 32; off >= 1; off >>= 1) {
    #pragma unroll
    for (int e = 0; e < NE; e++) p[e] += __shfl_xor(p[e], off);
  }
  if (lane == 0) {
    float l[NE];
    #pragma unroll
    for (int e = 0; e < NE; e++) l[e] = p[e] + rb[e];
    float m = l[0];
    #pragma unroll
    for (int e = 1; e < NE; e++) m = fmaxf(m, l[e]);
    float g[NE];
    #pragma unroll
    for (int e = 0; e < NE; e++) g[e] = __expf(l[e] - m);
    // top-2 by gate (== top-2 by logit); ties -> lower index first (jax top_k)
    int i0 = 0;
    #pragma unroll
    for (int e = 1; e < NE; e++) if (g[e] > g[i0]) i0 = e;
    int i1 = -1;
    #pragma unroll
    for (int e = 0; e < NE; e++) {
      if (e == i0) continue;
      if (i1 < 0 || g[e] > g[i1]) i1 = e;
    }
    float inv = 1.f / (g[i0] + g[i1]);
    tokE[t] = make_int2(i0, i1);
    tokG[t] = make_float2(g[i0] * inv, g[i1] * inv);
  }
}

// ---------------- K4: counts (LDS histogram) + prefix offsets + cursor init ----------------
// single block, 1024 threads
__global__ void count_offsets_kernel(const int2* __restrict__ tokE, int* __restrict__ offs,
                                     int* __restrict__ cursors) {
  __shared__ int hist[NE];
  if (threadIdx.x < NE) {
    hist[threadIdx.x] = 0;
    cursors[threadIdx.x * 16] = 0;   // 64B-padded cursors
  }
  __syncthreads();
  for (int t = threadIdx.x; t < NT; t += 1024) {
    int2 e = tokE[t];
    atomicAdd(&hist[e.x], 1);
    atomicAdd(&hist[e.y], 1);
  }
  __syncthreads();
  if (threadIdx.x == 0) {
    int tot = 0;
    for (int e = 0; e < NE; e++) {
      offs[e] = tot;
      tot += (hist[e] + 127) & ~127;
    }
    offs[NE] = tot;
  }
}

// ---------------- K5: fill slot metadata defaults ----------------
__global__ void fill_kernel(const int* __restrict__ offs, int* __restrict__ tok,
                            float* __restrict__ gate, int* __restrict__ sexp) {
  int s = blockIdx.x * 256 + threadIdx.x;
  int e = NE - 1;
  #pragma unroll
  for (int i = 0; i < NE; i++)
    if (s >= offs[i] && s < offs[i + 1]) e = i;
  sexp[s] = e;
  tok[s] = -1;
  gate[s] = 0.f;
}

// ---------------- K6: scatter assignments (wave-aggregated atomics) ----------------
__global__ void scatter_kernel(const int2* __restrict__ tokE, const float2* __restrict__ tokG,
                               const int* __restrict__ offs, int* __restrict__ cursors,
                               int* __restrict__ tok, float* __restrict__ gate) {
  int t = blockIdx.x * 256 + threadIdx.x;
  int lane = threadIdx.x & 63;
  int2 e = tokE[t];
  float2 g = tokG[t];
  #pragma unroll
  for (int k = 0; k < 2; k++) {
    int ek = k ? e.y : e.x;
    float gk = k ? g.y : g.x;
    #pragma unroll
    for (int ex = 0; ex < NE; ex++) {
      unsigned long long mask = __ballot(ek == ex);
      if (ek == ex) {
        int leader = __ffsll(mask) - 1;
        int rank = __popcll(mask & ((1ull << lane) - 1ull));
        int base = 0;
        if (lane == leader) base = atomicAdd(&cursors[ex * 16], __popcll(mask));
        base = __shfl(base, leader);
        int s = offs[ex] + base + rank;
        tok[s] = t;
        gate[s] = gk;
      }
    }
  }
}

// ---------------- K7: GEMM1  H = relu(x_gather @ W1 + b1), bf16 out ----------------
// grid (CAP/128, TF/128), block 256 (4 waves, 2x2 of 64x64); m97-style async staging
__global__ __launch_bounds__(256, 2) void gemm1_kernel(
    const u16* __restrict__ xb, const u16* __restrict__ w1t,
    const float* __restrict__ b1, const int* __restrict__ tok,
    const int* __restrict__ sexp, u16* __restrict__ H) {
  __shared__ u16 As[128 * 64];
  __shared__ u16 Bs[128 * 64];
  __shared__ int tokS[128];
  const int tid = threadIdx.x;
  const int s0 = blockIdx.x * 128;
  const int f0 = blockIdx.y * 128;
  const int e = sexp[s0];
  if (tid < 128) {
    int t = tok[s0 + tid];
    tokS[tid] = t < 0 ? 0 : t;  // padding rows read token 0 (result discarded)
  }
  __syncthreads();

  const int lane = tid & 63;
  const int wv = tid >> 6;
  const int srow = lane >> 3;        // 0..7 within 8-row chunk
  const int scol = (lane & 7) * 8;   // 0..56
  const int wm = (wv >> 1) * 64;
  const int wn = (wv & 1) * 64;
  const int mrow = lane & 15;
  const int koff = (lane >> 4) * 8;

  f32x4 zero = {0.f, 0.f, 0.f, 0.f};
  f32x4 acc[4][4];
  #pragma unroll
  for (int i = 0; i < 4; i++)
    #pragma unroll
    for (int j = 0; j < 4; j++) acc[i][j] = zero;

  const u16* bbase = w1t + ((size_t)e * TF + f0) * TD;

  for (int k0 = 0; k0 < TD; k0 += 64) {
    if (k0) __syncthreads();
    #pragma unroll
    for (int p = 0; p < 4; p++) {
      int row = wv * 32 + p * 8 + srow;
      load_lds16(xb + (size_t)tokS[row] * TD + k0 + scol, &As[(wv * 32 + p * 8) * 64]);
      load_lds16(bbase + (size_t)row * TD + k0 + scol, &Bs[(wv * 32 + p * 8) * 64]);
    }
    __syncthreads();
    #pragma unroll
    for (int ks = 0; ks < 2; ks++) {
      bf16x8 a[4], b[4];
      #pragma unroll
      for (int i = 0; i < 4; i++)
        a[i] = *reinterpret_cast<const bf16x8*>(&As[(wm + i * 16 + mrow) * 64 + ks * 32 + koff]);
      #pragma unroll
      for (int j = 0; j < 4; j++)
        b[j] = *reinterpret_cast<const bf16x8*>(&Bs[(wn + j * 16 + mrow) * 64 + ks * 32 + koff]);
      #pragma unroll
      for (int i = 0; i < 4; i++)
        #pragma unroll
        for (int j = 0; j < 4; j++)
          acc[i][j] = __builtin_amdgcn_mfma_f32_16x16x32_bf16(a[i], b[j], acc[i][j], 0, 0, 0);
    }
  }

  const int quad = lane >> 4;
  float bv[4];
  #pragma unroll
  for (int j = 0; j < 4; j++) bv[j] = b1[e * TF + f0 + wn + j * 16 + mrow];
  #pragma unroll
  for (int i = 0; i < 4; i++) {
    #pragma unroll
    for (int r = 0; r < 4; r++) {
      int row = s0 + wm + i * 16 + quad * 4 + r;
      u16* hrow = H + (size_t)row * TF + f0;
      #pragma unroll
      for (int j = 0; j < 4; j++) {
        float v = acc[i][j][r] + bv[j];
        v = v > 0.f ? v : 0.f;
        hrow[wn + j * 16 + mrow] = f2bf(v);
      }
    }
  }
}

// ---------------- K8: GEMM2  out[tok] += gate * (H @ W2 + b2) ----------------
// grid (CAP/128, TD/128), block 256; m97-style async staging
__global__ __launch_bounds__(256, 2) void gemm2_kernel(
    const u16* __restrict__ H, const u16* __restrict__ w2t,
    const float* __restrict__ b2, const int* __restrict__ tok,
    const float* __restrict__ gate, const int* __restrict__ sexp,
    float* __restrict__ out) {
  __shared__ u16 As[128 * 64];
  __shared__ u16 Bs[128 * 64];
  __shared__ int tokS[128];
  __shared__ float gateS[128];
  const int tid = threadIdx.x;
  const int s0 = blockIdx.x * 128;
  const int d0 = blockIdx.y * 128;
  const int e = sexp[s0];
  if (tid < 128) {
    tokS[tid] = tok[s0 + tid];
    gateS[tid] = gate[s0 + tid];
  }
  __syncthreads();

  const int lane = tid & 63;
  const int wv = tid >> 6;
  const int srow = lane >> 3;
  const int scol = (lane & 7) * 8;
  const int wm = (wv >> 1) * 64;
  const int wn = (wv & 1) * 64;
  const int mrow = lane & 15;
  const int koff = (lane >> 4) * 8;

  f32x4 zero = {0.f, 0.f, 0.f, 0.f};
  f32x4 acc[4][4];
  #pragma unroll
  for (int i = 0; i < 4; i++)
    #pragma unroll
    for (int j = 0; j < 4; j++) acc[i][j] = zero;

  const u16* bbase = w2t + ((size_t)e * TD + d0) * TF;

  for (int k0 = 0; k0 < TF; k0 += 64) {
    if (k0) __syncthreads();
    #pragma unroll
    for (int p = 0; p < 4; p++) {
      int row = wv * 32 + p * 8 + srow;
      load_lds16(H + (size_t)(s0 + row) * TF + k0 + scol, &As[(wv * 32 + p * 8) * 64]);
      load_lds16(bbase + (size_t)row * TF + k0 + scol, &Bs[(wv * 32 + p * 8) * 64]);
    }
    __syncthreads();
    #pragma unroll
    for (int ks = 0; ks < 2; ks++) {
      bf16x8 a[4], b[4];
      #pragma unroll
      for (int i = 0; i < 4; i++)
        a[i] = *reinterpret_cast<const bf16x8*>(&As[(wm + i * 16 + mrow) * 64 + ks * 32 + koff]);
      #pragma unroll
      for (int j = 0; j < 4; j++)
        b[j] = *reinterpret_cast<const bf16x8*>(&Bs[(wn + j * 16 + mrow) * 64 + ks * 32 + koff]);
      #pragma unroll
      for (int i = 0; i < 4; i++)
        #pragma unroll
        for (int j = 0; j < 4; j++)
          acc[i][j] = __builtin_amdgcn_mfma_f32_16x16x32_bf16(a[i], b[j], acc[i][j], 0, 0, 0);
    }
  }

  const int quad = lane >> 4;
  float bv[4];
  #pragma unroll
  for (int j = 0; j < 4; j++) bv[j] = b2[e * TD + d0 + wn + j * 16 + mrow];
  #pragma unroll
  for (int i = 0; i < 4; i++) {
    #pragma unroll
    for (int r = 0; r < 4; r++) {
      int rl = wm + i * 16 + quad * 4 + r;
      int t = tokS[rl];
      if (t < 0) continue;
      float g = gateS[rl];
      float* orow = out + (size_t)t * TD + d0;
      #pragma unroll
      for (int j = 0; j < 4; j++) {
        atomicAdd(&orow[wn + j * 16 + mrow], g * (acc[i][j][r] + bv[j]));
      }
    }
  }
}

extern "C" void kernel_launch(void* const* d_in, const int* in_sizes, int n_in,
                              void* d_out, int out_size, void* d_ws, size_t ws_size,
                              hipStream_t stream) {
  const float* x  = (const float*)d_in[0];
  const float* rw = (const float*)d_in[1];
  const float* rb = (const float*)d_in[2];
  const float* w1 = (const float*)d_in[3];
  const float* b1 = (const float*)d_in[4];
  const float* w2 = (const float*)d_in[5];
  const float* b2 = (const float*)d_in[6];
  float* out = (float*)d_out;

  char* w = (char*)d_ws;
  u16* xb   = (u16*)w;            w += (size_t)NT * TD * 2;         // 8 MB
  u16* w1t  = (u16*)w;            w += (size_t)NE * TD * TF * 2;    // 16 MB
  u16* w2t  = (u16*)w;            w += (size_t)NE * TF * TD * 2;    // 16 MB
  u16* H    = (u16*)w;            w += (size_t)CAP * TF * 2;        // 68 MB
  int* tok  = (int*)w;            w += (size_t)CAP * 4;
  float* gate = (float*)w;        w += (size_t)CAP * 4;
  int* sexp = (int*)w;            w += (size_t)CAP * 4;
  int2* tokE = (int2*)w;          w += (size_t)NT * 8;
  float2* tokG = (float2*)w;      w += (size_t)NT * 8;
  int* cursors = (int*)w;         w += 1024;                        // 64B-padded x8
  int* offs = (int*)w;            w += 256;

  // 1. zero output
  zero_kernel<<<dim3((NT * TD) / (256 * 4)), dim3(256), 0, stream>>>(out);
  // 2. transpose+convert w1 [E][D][F] -> w1t [E][F][D]
  transpose_cvt_kernel<<<dim3(TF / 32, TD / 32, NE), dim3(32, 8), 0, stream>>>(w1, w1t, TD, TF);
  // 3. transpose+convert w2 [E][F][D] -> w2t [E][D][F]
  transpose_cvt_kernel<<<dim3(TD / 32, TF / 32, NE), dim3(32, 8), 0, stream>>>(w2, w2t, TF, TD);
  // 4. router (writes tokE/tokG + bf16 x) — no atomics
  router_kernel<<<dim3(NT / 4), dim3(256), 0, stream>>>(x, rw, rb, tokE, tokG, xb);
  // 5. counts + offsets + cursor init (single block)
  count_offsets_kernel<<<dim3(1), dim3(1024), 0, stream>>>(tokE, offs, cursors);
  // 6. fill slot defaults
  fill_kernel<<<dim3(CAP / 256), dim3(256), 0, stream>>>(offs, tok, gate, sexp);
  // 7. scatter assignments (wave-aggregated)
  scatter_kernel<<<dim3(NT / 256), dim3(256), 0, stream>>>(tokE, tokG, offs, cursors, tok, gate);
  // 8. GEMM1
  gemm1_kernel<<<dim3(CAP / 128, TF / 128), dim3(256), 0, stream>>>(xb, w1t, b1, tok, sexp, H);
  // 9. GEMM2 + scatter-add epilogue
  gemm2_kernel<<<dim3(CAP / 128, TD / 128), dim3(256), 0, stream>>>(H, w2t, b2, tok, gate, sexp, out);
}